// Round 12
// baseline (1078.223 us; speedup 1.0000x reference)
//
#include <hip/hip_runtime.h>
#include <hip/hip_bf16.h>

// LSTM2: B=1024, T=1024, H=64. R12: R9 skeleton, scratch ELIMINATED --
// cells computed directly on MFMA accumulators (D-layout is lane-local:
// lane (quad,m<4) holds gates i,f,g,o [tiles q=0..3] for units 16w+quad*4+r,
// batch m). Removes from the serial chain: 8 scr writes + 2 scr reads +
// lgkmcnt waits + all scratch bank conflicts + R10's transpose join.
// 256 blocks (4 batches) x 4 waves, 1 barrier/step, double-buffered h.
// Phase A (m<4): cell1(t) on a1 regs -> h1(t); cell2(t-1) on a2 regs ->
//   h2(t-1) + head partial.  barrier.
// Phase B: finalize out(t-1) [wave0, in MFMA shadow]; read h frags;
//   a1(t+1) = W1.h1_t + x*wx + b1 (issued FIRST: consumed first next iter);
//   a2(t)   = W2.h1_t + W3.h2_{t-1} + b2.  MFMA latency is off-chain
//   (results consumed next iteration).
// Layouts (m89/m91/m120): A[m=lane&15][k=(lane>>4)*8+j],
// B[k=(lane>>4)*8+j][n=lane&15], C/D: row=(lane>>4)*4+reg, col=lane&15.

typedef _Float16 f16x8 __attribute__((ext_vector_type(8)));
typedef _Float16 f16x4 __attribute__((ext_vector_type(4)));
typedef float    f32x4 __attribute__((ext_vector_type(4)));

namespace {
constexpr int Bb = 1024;
constexpr int Tt = 1024;
constexpr int NBat = 4;    // batches per block
constexpr int HSTR = 72;   // f16 stride per batch row of h
constexpr int XSTR = 1025; // f32 stride per batch row of x

__device__ __forceinline__ float sigm(float x) {
    float e = __builtin_amdgcn_exp2f(-1.4426950408889634f * x);
    return __builtin_amdgcn_rcpf(1.0f + e);
}
__device__ __forceinline__ float tanh_f(float x) {
    float e = __builtin_amdgcn_exp2f(-2.8853900817779268f * x);
    return __builtin_amdgcn_rcpf(1.0f + e) * 2.0f - 1.0f;
}
// Dtype sniff (proven R2-R11).
__device__ __forceinline__ bool detect_f32(const void* w) {
    const unsigned short* p = (const unsigned short*)w;
    int sane = 0;
    for (int i = 0; i < 64; ++i) {
        int e = (p[2 * i] >> 7) & 0xFF;
        if (e >= 107 && e <= 129) ++sane;
    }
    return sane < 32;
}
__device__ __forceinline__ float ld(const void* p, int i, bool f32) {
    return f32 ? ((const float*)p)[i]
               : __bfloat162float(((const __hip_bfloat16*)p)[i]);
}
__device__ __forceinline__ void st(void* p, int i, float v, bool f32) {
    if (f32) ((float*)p)[i] = v;
    else     ((__hip_bfloat16*)p)[i] = __float2bfloat16(v);
}
} // namespace

__global__ __launch_bounds__(256, 1) void lstm2_kernel(
    const void* __restrict__ x,      // [B, T]
    const void* __restrict__ w_ih1,  // [256, 1]
    const void* __restrict__ w_hh1,  // [256, 64]
    const void* __restrict__ b_ih1,  // [256]
    const void* __restrict__ b_hh1,  // [256]
    const void* __restrict__ w_ih2,  // [256, 64]
    const void* __restrict__ w_hh2,  // [256, 64]
    const void* __restrict__ b_ih2,  // [256]
    const void* __restrict__ b_hh2,  // [256]
    const void* __restrict__ w_lin,  // [1, 64]
    const void* __restrict__ b_lin,  // [1]
    void* __restrict__ out)          // [B, T]
{
    const int tid  = threadIdx.x;
    const int lane = tid & 63;
    const int w    = tid >> 6;       // wave -> unit group 16w..16w+15
    const int m    = lane & 15;      // MFMA col (batch; valid m<NBat)
    const int quad = lane >> 4;
    const int bb   = blockIdx.x * NBat;

    const bool f32 = detect_f32(w_hh1);

    __shared__ float                  xs[NBat * XSTR];
    __shared__ __align__(16) _Float16 h1buf[2][16 * HSTR];  // double-buffered
    __shared__ __align__(16) _Float16 h2buf[2][16 * HSTR];
    __shared__ float                  headl[2][16];         // [buf][w*4+b]

    // ---- stage x + zero h buffers (rows >= NBat stay 0 forever) ----
    for (int i = tid; i < NBat * 1024; i += 256)
        xs[(i >> 10) * XSTR + (i & 1023)] = ld(x, (bb + (i >> 10)) * Tt + (i & 1023), f32);
    for (int i = tid; i < 16 * HSTR; i += 256) {
        h1buf[0][i] = (_Float16)0; h1buf[1][i] = (_Float16)0;
        h2buf[0][i] = (_Float16)0; h2buf[1][i] = (_Float16)0;
    }

    // ---- one-time: A-fragments (96 VGPRs): elem j = W[64q+16w+m][32s+quad*8+j]
    f16x8 wf1[4][2], wf2[4][2], wf3[4][2];
    if (f32) {
        const float* W1 = (const float*)w_hh1;
        const float* W2 = (const float*)w_ih2;
        const float* W3 = (const float*)w_hh2;
#pragma unroll
        for (int q = 0; q < 4; ++q) {
            const int row = 64 * q + 16 * w + m;
#pragma unroll
            for (int s = 0; s < 2; ++s) {
                const int base = row * 64 + 32 * s + quad * 8;
#pragma unroll
                for (int j = 0; j < 8; ++j) {
                    wf1[q][s][j] = (_Float16)W1[base + j];
                    wf2[q][s][j] = (_Float16)W2[base + j];
                    wf3[q][s][j] = (_Float16)W3[base + j];
                }
            }
        }
    } else {
        const __hip_bfloat16* W1 = (const __hip_bfloat16*)w_hh1;
        const __hip_bfloat16* W2 = (const __hip_bfloat16*)w_ih2;
        const __hip_bfloat16* W3 = (const __hip_bfloat16*)w_hh2;
#pragma unroll
        for (int q = 0; q < 4; ++q) {
            const int row = 64 * q + 16 * w + m;
#pragma unroll
            for (int s = 0; s < 2; ++s) {
                const int base = row * 64 + 32 * s + quad * 8;
#pragma unroll
                for (int j = 0; j < 8; ++j) {
                    wf1[q][s][j] = (_Float16)__bfloat162float(W1[base + j]);
                    wf2[q][s][j] = (_Float16)__bfloat162float(W2[base + j]);
                    wf3[q][s][j] = (_Float16)__bfloat162float(W3[base + j]);
                }
            }
        }
    }
    f32x4 b1v[4], b2v[4], wxv[4];
#pragma unroll
    for (int q = 0; q < 4; ++q)
#pragma unroll
        for (int r = 0; r < 4; ++r) {
            const int row = 64 * q + 16 * w + quad * 4 + r;
            b1v[q][r] = ld(b_ih1, row, f32) + ld(b_hh1, row, f32);
            b2v[q][r] = ld(b_ih2, row, f32) + ld(b_hh2, row, f32);
            wxv[q][r] = ld(w_ih1, row, f32);
        }
    // head weights for this lane's 4 units (valid for cell lanes m<NBat)
    float wlq[4];
#pragma unroll
    for (int r = 0; r < 4; ++r) wlq[r] = ld(w_lin, 16 * w + quad * 4 + r, f32);
    const float blin = ld(b_lin, 0, f32);

    f32x4 a1[4], a2[4];                 // carried accumulators (gate tiles)
    f32x4 c1 = {0,0,0,0}, c2 = {0,0,0,0};  // cell state per r (lanes m<NBat)
    __syncthreads();   // xs + zeroed h bufs visible

    // ---- prologue: a1(0) = x_0*wx + b1 in registers (h1_{-1}=0) ----
    {
        const float x0 = xs[(m & (NBat - 1)) * XSTR];
#pragma unroll
        for (int q = 0; q < 4; ++q)
#pragma unroll
            for (int r = 0; r < 4; ++r) a1[q][r] = fmaf(x0, wxv[q][r], b1v[q][r]);
    }

    for (int t = 0; t < Tt; ++t) {
        const int cur = t & 1;
        // ---- Phase A (lanes m<NBat): cells directly on accumulators ----
        if (m < NBat) {
            f16x4 h1o;
#pragma unroll
            for (int r = 0; r < 4; ++r) {
                float ig = sigm(a1[0][r]), fg = sigm(a1[1][r]);
                float gg = tanh_f(a1[2][r]), og = sigm(a1[3][r]);
                c1[r] = fmaf(fg, c1[r], ig * gg);
                h1o[r] = (_Float16)(og * tanh_f(c1[r]));
            }
            *(f16x4*)(h1buf[cur] + m * HSTR + 16 * w + quad * 4) = h1o;
            if (t > 0) {
                f16x4 h2o;
                float p = 0.0f;
#pragma unroll
                for (int r = 0; r < 4; ++r) {
                    float ig = sigm(a2[0][r]), fg = sigm(a2[1][r]);
                    float gg = tanh_f(a2[2][r]), og = sigm(a2[3][r]);
                    c2[r] = fmaf(fg, c2[r], ig * gg);
                    float h = og * tanh_f(c2[r]);
                    h2o[r] = (_Float16)h;
                    p = fmaf(h, wlq[r], p);
                }
                *(f16x4*)(h2buf[cur] + m * HSTR + 16 * w + quad * 4) = h2o;
                p += __shfl_xor(p, 16);       // reduce over quads (same m, all
                p += __shfl_xor(p, 32);       // participants active)
                if (quad == 0) headl[cur][w * 4 + m] = p;
            }
        }
        __syncthreads();                      // THE barrier: h_t / partials

        // ---- Phase B: finalize head (MFMA shadow) + MFMA ----
        if (t > 0 && tid < NBat) {
            float s = blin;
#pragma unroll
            for (int k = 0; k < 4; ++k) s += headl[cur][k * 4 + tid];
            st(out, (bb + tid) * Tt + (t - 1), s, f32);
        }
        const f16x8 bh1a = *(const f16x8*)(h1buf[cur] + m * HSTR + quad * 8);
        const f16x8 bh1b = *(const f16x8*)(h1buf[cur] + m * HSTR + 32 + quad * 8);
        const f16x8 bh2a = *(const f16x8*)(h2buf[cur] + m * HSTR + quad * 8);
        const f16x8 bh2b = *(const f16x8*)(h2buf[cur] + m * HSTR + 32 + quad * 8);
        const float xtn  = xs[(m & (NBat - 1)) * XSTR + ((t + 1 < Tt) ? t + 1 : t)];
        // a1(t+1) first: consumed first in next Phase A
#pragma unroll
        for (int q = 0; q < 4; ++q) {
            f32x4 i1;
#pragma unroll
            for (int r = 0; r < 4; ++r) i1[r] = fmaf(xtn, wxv[q][r], b1v[q][r]);
            i1    = __builtin_amdgcn_mfma_f32_16x16x32_f16(wf1[q][0], bh1a, i1, 0, 0, 0);
            a1[q] = __builtin_amdgcn_mfma_f32_16x16x32_f16(wf1[q][1], bh1b, i1, 0, 0, 0);
        }
#pragma unroll
        for (int q = 0; q < 4; ++q) {
            f32x4 p2 = __builtin_amdgcn_mfma_f32_16x16x32_f16(wf2[q][0], bh1a, b2v[q], 0, 0, 0);
            p2 = __builtin_amdgcn_mfma_f32_16x16x32_f16(wf2[q][1], bh1b, p2, 0, 0, 0);
            p2 = __builtin_amdgcn_mfma_f32_16x16x32_f16(wf3[q][0], bh2a, p2, 0, 0, 0);
            a2[q] = __builtin_amdgcn_mfma_f32_16x16x32_f16(wf3[q][1], bh2b, p2, 0, 0, 0);
        }
        // no second barrier: h double-buffered (B(t-1) reads of buf cur^1 are
        // separated from A(t+1) writes by barrier(t) -- R9-proven argument)
    }

    // ---- epilogue: cell2(T-1) + head + out[T-1] ----
    if (m < NBat) {
        float p = 0.0f;
#pragma unroll
        for (int r = 0; r < 4; ++r) {
            float ig = sigm(a2[0][r]), fg = sigm(a2[1][r]);
            float gg = tanh_f(a2[2][r]), og = sigm(a2[3][r]);
            c2[r] = fmaf(fg, c2[r], ig * gg);
            p = fmaf(og * tanh_f(c2[r]), wlq[r], p);
        }
        p += __shfl_xor(p, 16);
        p += __shfl_xor(p, 32);
        if (quad == 0) headl[0][w * 4 + m] = p;
    }
    __syncthreads();
    if (tid < NBat) {
        float s = blin;
#pragma unroll
        for (int k = 0; k < 4; ++k) s += headl[0][k * 4 + tid];
        st(out, (bb + tid) * Tt + (Tt - 1), s, f32);
    }
}

extern "C" void kernel_launch(void* const* d_in, const int* in_sizes, int n_in,
                              void* d_out, int out_size, void* d_ws, size_t ws_size,
                              hipStream_t stream)
{
    (void)in_sizes; (void)n_in; (void)out_size; (void)d_ws; (void)ws_size;
    lstm2_kernel<<<dim3(Bb / NBat), dim3(256), 0, stream>>>(
        d_in[0], d_in[1], d_in[2], d_in[3], d_in[4], d_in[5],
        d_in[6], d_in[7], d_in[8], d_in[9], d_in[10], d_out);
}

// Round 13
// 902.767 us; speedup vs baseline: 1.1944x; 1.1944x over previous
//
#include <hip/hip_runtime.h>
#include <hip/hip_bf16.h>

// LSTM2: B=1024, T=1024, H=64. R13: R9 skeleton + gate-interleaved weight
// rows (transpose pre-baked into A-frag load) + XOR-swizzled direct f32x4
// scratch stores.
// 256 blocks (4 batches) x 4 waves, 1 barrier/step, double-buffered h.
// A-frag tile row 4*u+g -> memory row 64*g + 16w + 4q + u, so D regs
// a[q][0..3] = gates i,f,g,o of unit 16w+4q+quad, batch m. Phase B stores
// each accumulator directly (no transpose join, R10 lesson) at swizzled row
// srow(m*16+q*4+quad) (writes 2-way=free, R11-verified). Phase A: ONE
// ds_read_b128 per layer per lane (row=lane: batch=lane>>4, unit=lane&15),
// 1 cell eval per lane per layer (issue-cost lesson of R12: evals must
// spread across all 64 lanes). Head finalize in MFMA completion shadow.
// Layouts (m89/m91/m120): A[m=lane&15][k=(lane>>4)*8+j],
// B[k=(lane>>4)*8+j][n=lane&15], C/D: row=(lane>>4)*4+reg, col=lane&15.

typedef _Float16 f16x8 __attribute__((ext_vector_type(8)));
typedef float    f32x4 __attribute__((ext_vector_type(4)));

namespace {
constexpr int Bb = 1024;
constexpr int Tt = 1024;
constexpr int NBat = 4;    // batches per block
constexpr int HSTR = 72;   // f16 stride per batch row of h
constexpr int XSTR = 1025; // f32 stride per batch row of x

__device__ __forceinline__ int srow(int row) {      // XOR bank swizzle
    return row ^ ((row >> 3) & 7);
}
__device__ __forceinline__ float sigm(float x) {
    float e = __builtin_amdgcn_exp2f(-1.4426950408889634f * x);
    return __builtin_amdgcn_rcpf(1.0f + e);
}
__device__ __forceinline__ float tanh_f(float x) {
    float e = __builtin_amdgcn_exp2f(-2.8853900817779268f * x);
    return __builtin_amdgcn_rcpf(1.0f + e) * 2.0f - 1.0f;
}
// Dtype sniff (proven R2-R12).
__device__ __forceinline__ bool detect_f32(const void* w) {
    const unsigned short* p = (const unsigned short*)w;
    int sane = 0;
    for (int i = 0; i < 64; ++i) {
        int e = (p[2 * i] >> 7) & 0xFF;
        if (e >= 107 && e <= 129) ++sane;
    }
    return sane < 32;
}
__device__ __forceinline__ float ld(const void* p, int i, bool f32) {
    return f32 ? ((const float*)p)[i]
               : __bfloat162float(((const __hip_bfloat16*)p)[i]);
}
__device__ __forceinline__ void st(void* p, int i, float v, bool f32) {
    if (f32) ((float*)p)[i] = v;
    else     ((__hip_bfloat16*)p)[i] = __float2bfloat16(v);
}
} // namespace

__global__ __launch_bounds__(256, 1) void lstm2_kernel(
    const void* __restrict__ x,      // [B, T]
    const void* __restrict__ w_ih1,  // [256, 1]
    const void* __restrict__ w_hh1,  // [256, 64]
    const void* __restrict__ b_ih1,  // [256]
    const void* __restrict__ b_hh1,  // [256]
    const void* __restrict__ w_ih2,  // [256, 64]
    const void* __restrict__ w_hh2,  // [256, 64]
    const void* __restrict__ b_ih2,  // [256]
    const void* __restrict__ b_hh2,  // [256]
    const void* __restrict__ w_lin,  // [1, 64]
    const void* __restrict__ b_lin,  // [1]
    void* __restrict__ out)          // [B, T]
{
    const int tid  = threadIdx.x;
    const int lane = tid & 63;
    const int w    = tid >> 6;       // wave -> unit group 16w..16w+15
    const int m    = lane & 15;      // MFMA col (batch; valid m<NBat)
    const int quad = lane >> 4;
    const int bb   = blockIdx.x * NBat;

    const bool f32 = detect_f32(w_hh1);

    __shared__ float                  xs[NBat * XSTR];
    __shared__ __align__(16) _Float16 h1buf[2][16 * HSTR];  // double-buffered
    __shared__ __align__(16) _Float16 h2buf[2][16 * HSTR];
    __shared__ __align__(16) float    scr1[4][64 * 4];      // per-wave, swizzled
    __shared__ __align__(16) float    scr2[4][64 * 4];
    __shared__ float                  headl[2][16];         // [buf][w*4+b]

    // ---- stage x + zero h buffers (rows >= NBat stay 0 forever) ----
    for (int i = tid; i < NBat * 1024; i += 256)
        xs[(i >> 10) * XSTR + (i & 1023)] = ld(x, (bb + (i >> 10)) * Tt + (i & 1023), f32);
    for (int i = tid; i < 16 * HSTR; i += 256) {
        h1buf[0][i] = (_Float16)0; h1buf[1][i] = (_Float16)0;
        h2buf[0][i] = (_Float16)0; h2buf[1][i] = (_Float16)0;
    }

    // ---- A-fragments, GATE-INTERLEAVED rows (96 VGPRs) ----
    // tile row (lane&15) = 4*u_loc + g  ->  mem row 64*g + 16w + 4q + u_loc
    const int arow = lane & 15;
    const int g_ld = arow & 3;
    const int u_ld = arow >> 2;
    f16x8 wf1[4][2], wf2[4][2], wf3[4][2];
    if (f32) {
        const float* W1 = (const float*)w_hh1;
        const float* W2 = (const float*)w_ih2;
        const float* W3 = (const float*)w_hh2;
#pragma unroll
        for (int q = 0; q < 4; ++q) {
            const int row = 64 * g_ld + 16 * w + 4 * q + u_ld;
#pragma unroll
            for (int s = 0; s < 2; ++s) {
                const int base = row * 64 + 32 * s + quad * 8;
#pragma unroll
                for (int j = 0; j < 8; ++j) {
                    wf1[q][s][j] = (_Float16)W1[base + j];
                    wf2[q][s][j] = (_Float16)W2[base + j];
                    wf3[q][s][j] = (_Float16)W3[base + j];
                }
            }
        }
    } else {
        const __hip_bfloat16* W1 = (const __hip_bfloat16*)w_hh1;
        const __hip_bfloat16* W2 = (const __hip_bfloat16*)w_ih2;
        const __hip_bfloat16* W3 = (const __hip_bfloat16*)w_hh2;
#pragma unroll
        for (int q = 0; q < 4; ++q) {
            const int row = 64 * g_ld + 16 * w + 4 * q + u_ld;
#pragma unroll
            for (int s = 0; s < 2; ++s) {
                const int base = row * 64 + 32 * s + quad * 8;
#pragma unroll
                for (int j = 0; j < 8; ++j) {
                    wf1[q][s][j] = (_Float16)__bfloat162float(W1[base + j]);
                    wf2[q][s][j] = (_Float16)__bfloat162float(W2[base + j]);
                    wf3[q][s][j] = (_Float16)__bfloat162float(W3[base + j]);
                }
            }
        }
    }
    // bias/wx per (tile q, gate r): D row r of tile q = gate r, unit 16w+4q+quad
    f32x4 b1v[4], b2v[4], wxv[4];
#pragma unroll
    for (int q = 0; q < 4; ++q)
#pragma unroll
        for (int r = 0; r < 4; ++r) {
            const int row = 64 * r + 16 * w + 4 * q + quad;
            b1v[q][r] = ld(b_ih1, row, f32) + ld(b_hh1, row, f32);
            b2v[q][r] = ld(b_ih2, row, f32) + ld(b_hh2, row, f32);
            wxv[q][r] = ld(w_ih1, row, f32);
        }
    // cell mapping: lane -> (batch cb, unit 16w+uo); 1 eval/lane/layer
    const int cb = lane >> 4;
    const int uo = lane & 15;
    const int cidx = srow(lane) * 4;
    const float wl_u = ld(w_lin, 16 * w + uo, f32);
    const float blin = ld(b_lin, 0, f32);
    float c1 = 0.0f, c2 = 0.0f;
    __syncthreads();   // xs + zeroed h bufs visible

    // ---- prologue: pre1(0) = x_0*wx + b1 -> scr1 (swizzled, own-wave) ----
    if (m < NBat) {
        const float x0 = xs[m * XSTR];
#pragma unroll
        for (int q = 0; q < 4; ++q) {
            f32x4 v;
#pragma unroll
            for (int r = 0; r < 4; ++r) v[r] = fmaf(x0, wxv[q][r], b1v[q][r]);
            *(f32x4*)&scr1[w][srow(m * 16 + q * 4 + quad) * 4] = v;
        }
    }
    // no barrier: A(0) reads own-wave scratch (in-order DS)

    for (int t = 0; t < Tt; ++t) {
        const int cur = t & 1;
        // ---- Phase A: 1 b128 read + 1 eval per lane per layer ----
        {
            const f32x4 g = *(const f32x4*)&scr1[w][cidx];   // i,f,g,o
            float ig = sigm(g[0]), fg = sigm(g[1]);
            float gg = tanh_f(g[2]), og = sigm(g[3]);
            c1 = fmaf(fg, c1, ig * gg);
            h1buf[cur][cb * HSTR + 16 * w + uo] = (_Float16)(og * tanh_f(c1));
        }
        if (t > 0) {
            const f32x4 g = *(const f32x4*)&scr2[w][cidx];
            float ig = sigm(g[0]), fg = sigm(g[1]);
            float gg = tanh_f(g[2]), og = sigm(g[3]);
            c2 = fmaf(fg, c2, ig * gg);
            float h = og * tanh_f(c2);
            h2buf[cur][cb * HSTR + 16 * w + uo] = (_Float16)h;
            float p = h * wl_u;               // reduce over uo (same cb)
            p += __shfl_xor(p, 1); p += __shfl_xor(p, 2);
            p += __shfl_xor(p, 4); p += __shfl_xor(p, 8);
            if (uo == 0) headl[cur][w * 4 + cb] = p;
        }
        __syncthreads();                      // THE barrier: h_t / partials

        // ---- Phase B: MFMA (a1 first), head finalize + stores in shadow ----
        const f16x8 bh1a = *(const f16x8*)(h1buf[cur] + m * HSTR + quad * 8);
        const f16x8 bh1b = *(const f16x8*)(h1buf[cur] + m * HSTR + 32 + quad * 8);
        const f16x8 bh2a = *(const f16x8*)(h2buf[cur] + m * HSTR + quad * 8);
        const f16x8 bh2b = *(const f16x8*)(h2buf[cur] + m * HSTR + 32 + quad * 8);
        const float xtn  = xs[(m & (NBat - 1)) * XSTR + ((t + 1 < Tt) ? t + 1 : t)];
        f32x4 a1[4], a2[4];
#pragma unroll
        for (int q = 0; q < 4; ++q) {         // a1(t+1): consumed first next A
            f32x4 i1;
#pragma unroll
            for (int r = 0; r < 4; ++r) i1[r] = fmaf(xtn, wxv[q][r], b1v[q][r]);
            i1    = __builtin_amdgcn_mfma_f32_16x16x32_f16(wf1[q][0], bh1a, i1, 0, 0, 0);
            a1[q] = __builtin_amdgcn_mfma_f32_16x16x32_f16(wf1[q][1], bh1b, i1, 0, 0, 0);
        }
#pragma unroll
        for (int q = 0; q < 4; ++q) {         // a2(t)
            f32x4 p2 = __builtin_amdgcn_mfma_f32_16x16x32_f16(wf2[q][0], bh1a, b2v[q], 0, 0, 0);
            p2 = __builtin_amdgcn_mfma_f32_16x16x32_f16(wf2[q][1], bh1b, p2, 0, 0, 0);
            p2 = __builtin_amdgcn_mfma_f32_16x16x32_f16(wf3[q][0], bh2a, p2, 0, 0, 0);
            a2[q] = __builtin_amdgcn_mfma_f32_16x16x32_f16(wf3[q][1], bh2b, p2, 0, 0, 0);
        }
        if (t > 0 && tid < NBat) {            // finalize out(t-1) in MFMA shadow
            float s = blin;
#pragma unroll
            for (int k = 0; k < 4; ++k) s += headl[cur][k * 4 + tid];
            st(out, (bb + tid) * Tt + (t - 1), s, f32);
        }
        if (m < NBat) {                       // direct f32x4 stores, swizzled
#pragma unroll
            for (int q = 0; q < 4; ++q)
                *(f32x4*)&scr1[w][srow(m * 16 + q * 4 + quad) * 4] = a1[q];
#pragma unroll
            for (int q = 0; q < 4; ++q)
                *(f32x4*)&scr2[w][srow(m * 16 + q * 4 + quad) * 4] = a2[q];
        }
        // no second barrier: h double-buffered; scratch per-wave in-order
    }

    // ---- epilogue: cell2(T-1) + head + out[T-1] ----
    {
        const f32x4 g = *(const f32x4*)&scr2[w][cidx];
        float ig = sigm(g[0]), fg = sigm(g[1]);
        float gg = tanh_f(g[2]), og = sigm(g[3]);
        c2 = fmaf(fg, c2, ig * gg);
        float h = og * tanh_f(c2);
        float p = h * wl_u;
        p += __shfl_xor(p, 1); p += __shfl_xor(p, 2);
        p += __shfl_xor(p, 4); p += __shfl_xor(p, 8);
        if (uo == 0) headl[0][w * 4 + cb] = p;
    }
    __syncthreads();
    if (tid < NBat) {
        float s = blin;
#pragma unroll
        for (int k = 0; k < 4; ++k) s += headl[0][k * 4 + tid];
        st(out, (bb + tid) * Tt + (Tt - 1), s, f32);
    }
}

extern "C" void kernel_launch(void* const* d_in, const int* in_sizes, int n_in,
                              void* d_out, int out_size, void* d_ws, size_t ws_size,
                              hipStream_t stream)
{
    (void)in_sizes; (void)n_in; (void)out_size; (void)d_ws; (void)ws_size;
    lstm2_kernel<<<dim3(Bb / NBat), dim3(256), 0, stream>>>(
        d_in[0], d_in[1], d_in[2], d_in[3], d_in[4], d_in[5],
        d_in[6], d_in[7], d_in[8], d_in[9], d_in[10], d_out);
}

// Round 14
// 826.201 us; speedup vs baseline: 1.3050x; 1.0927x over previous
//
#include <hip/hip_runtime.h>
#include <hip/hip_bf16.h>

// LSTM2: B=1024, T=1024, H=64. R14: wave-specialized 2-stage pipeline.
// Key insight: L2 never feeds back into L1 -> the recurrence-critical path is
// only cell1(t) -> W1.h1(t) -> cell1(t+1). The a2/cell2/head pipeline (60% of
// per-step work) runs ONE STEP BEHIND on separate waves, overlapped.
// 256 blocks (4 batches) x 8 waves (512 thr):
//   P-waves 0-3 (interval t): a1(t)=W1.h1(t-1)+x_t (8 MFMA) -> scr1 ->
//     cell1(t) (1 eval/lane) -> h1buf[t&1].
//   Q-waves 4-7 (interval t): finalize out(t-2) [shadow]; a2(t-1)=W2.h1(t-1)
//     +W3.h2(t-2) (16 MFMA) -> scr2 -> cell2(t-1) -> h2buf[(t-1)&1] + head
//     partial -> headl[(t-1)&1].
// ONE barrier per interval. Parity audit: h1 W:t&1 R:(t-1)&1; h2 W:(t-1)&1
// R:t&1; headl W:(t-1)&1 R:t&1 -- all write!=read parity, reuse separated by
// a barrier. scr1/scr2 own-wave (in-order DS). R13 gate-interleaved A-frags
// (D regs = 4 gates of one unit) + XOR-swizzled direct f32x4 stores kept.
// Layouts (m89/m91/m120): A[m=lane&15][k=(lane>>4)*8+j],
// B[k=(lane>>4)*8+j][n=lane&15], C/D: row=(lane>>4)*4+reg, col=lane&15.

typedef _Float16 f16x8 __attribute__((ext_vector_type(8)));
typedef float    f32x4 __attribute__((ext_vector_type(4)));

namespace {
constexpr int Bb = 1024;
constexpr int Tt = 1024;
constexpr int NBat = 4;    // batches per block
constexpr int HSTR = 72;   // f16 stride per batch row of h
constexpr int XSTR = 1025; // f32 stride per batch row of x

__device__ __forceinline__ int srow(int row) {      // XOR bank swizzle (R11)
    return row ^ ((row >> 3) & 7);
}
__device__ __forceinline__ float sigm(float x) {
    float e = __builtin_amdgcn_exp2f(-1.4426950408889634f * x);
    return __builtin_amdgcn_rcpf(1.0f + e);
}
__device__ __forceinline__ float tanh_f(float x) {
    float e = __builtin_amdgcn_exp2f(-2.8853900817779268f * x);
    return __builtin_amdgcn_rcpf(1.0f + e) * 2.0f - 1.0f;
}
// Dtype sniff (proven R2-R13).
__device__ __forceinline__ bool detect_f32(const void* w) {
    const unsigned short* p = (const unsigned short*)w;
    int sane = 0;
    for (int i = 0; i < 64; ++i) {
        int e = (p[2 * i] >> 7) & 0xFF;
        if (e >= 107 && e <= 129) ++sane;
    }
    return sane < 32;
}
__device__ __forceinline__ float ld(const void* p, int i, bool f32) {
    return f32 ? ((const float*)p)[i]
               : __bfloat162float(((const __hip_bfloat16*)p)[i]);
}
__device__ __forceinline__ void st(void* p, int i, float v, bool f32) {
    if (f32) ((float*)p)[i] = v;
    else     ((__hip_bfloat16*)p)[i] = __float2bfloat16(v);
}
} // namespace

__global__ __launch_bounds__(512, 1) void lstm2_kernel(
    const void* __restrict__ x,      // [B, T]
    const void* __restrict__ w_ih1,  // [256, 1]
    const void* __restrict__ w_hh1,  // [256, 64]
    const void* __restrict__ b_ih1,  // [256]
    const void* __restrict__ b_hh1,  // [256]
    const void* __restrict__ w_ih2,  // [256, 64]
    const void* __restrict__ w_hh2,  // [256, 64]
    const void* __restrict__ b_ih2,  // [256]
    const void* __restrict__ b_hh2,  // [256]
    const void* __restrict__ w_lin,  // [1, 64]
    const void* __restrict__ b_lin,  // [1]
    void* __restrict__ out)          // [B, T]
{
    const int tid  = threadIdx.x;
    const int lane = tid & 63;
    const int w    = tid >> 6;       // wave 0..7
    const int gw   = w & 3;          // group-local wave -> unit group 16gw..
    const bool isP = w < 4;          // P: L1 fast loop; Q: L2 pipeline
    const int m    = lane & 15;      // MFMA col (batch; valid m<NBat)
    const int quad = lane >> 4;
    const int bb   = blockIdx.x * NBat;

    const bool f32 = detect_f32(w_hh1);

    __shared__ float                  xs[NBat * XSTR];
    __shared__ __align__(16) _Float16 h1buf[2][16 * HSTR];  // parity-buffered
    __shared__ __align__(16) _Float16 h2buf[2][16 * HSTR];
    __shared__ __align__(16) float    scr1[4][64 * 4];      // P-wave scratch
    __shared__ __align__(16) float    scr2[4][64 * 4];      // Q-wave scratch
    __shared__ float                  headl[2][16];         // [parity][gw*4+b]

    // ---- stage x + zero h buffers (rows >= NBat stay 0 forever) ----
    for (int i = tid; i < NBat * 1024; i += 512)
        xs[(i >> 10) * XSTR + (i & 1023)] = ld(x, (bb + (i >> 10)) * Tt + (i & 1023), f32);
    for (int i = tid; i < 16 * HSTR; i += 512) {
        h1buf[0][i] = (_Float16)0; h1buf[1][i] = (_Float16)0;
        h2buf[0][i] = (_Float16)0; h2buf[1][i] = (_Float16)0;
    }

    // ---- A-fragments, gate-interleaved rows (R13) ----
    // tile row (lane&15) = 4*u_loc + g -> mem row 64*g + 16*gw + 4q + u_loc
    const int arow = lane & 15;
    const int g_ld = arow & 3;
    const int u_ld = arow >> 2;
    f16x8 wfA[4][2], wfB[4][2];   // P: wfA=W1 (wfB zero); Q: wfA=W2, wfB=W3
    {
        const void* MA = isP ? w_hh1 : w_ih2;
#pragma unroll
        for (int q = 0; q < 4; ++q) {
            const int row = 64 * g_ld + 16 * gw + 4 * q + u_ld;
#pragma unroll
            for (int s = 0; s < 2; ++s) {
                const int base = row * 64 + 32 * s + quad * 8;
                if (f32) {
                    const float* A = (const float*)MA;
                    const float* B = (const float*)w_hh2;
#pragma unroll
                    for (int j = 0; j < 8; ++j) {
                        wfA[q][s][j] = (_Float16)A[base + j];
                        wfB[q][s][j] = isP ? (_Float16)0.0f : (_Float16)B[base + j];
                    }
                } else {
                    const __hip_bfloat16* A = (const __hip_bfloat16*)MA;
                    const __hip_bfloat16* B = (const __hip_bfloat16*)w_hh2;
#pragma unroll
                    for (int j = 0; j < 8; ++j) {
                        wfA[q][s][j] = (_Float16)__bfloat162float(A[base + j]);
                        wfB[q][s][j] = isP ? (_Float16)0.0f
                                           : (_Float16)__bfloat162float(B[base + j]);
                    }
                }
            }
        }
    }
    // bias / wx per (tile q, gate r): D row r of tile q = gate r, unit 16gw+4q+quad
    f32x4 bv[4], wxv[4];
#pragma unroll
    for (int q = 0; q < 4; ++q)
#pragma unroll
        for (int r = 0; r < 4; ++r) {
            const int row = 64 * r + 16 * gw + 4 * q + quad;
            bv[q][r] = isP ? (ld(b_ih1, row, f32) + ld(b_hh1, row, f32))
                           : (ld(b_ih2, row, f32) + ld(b_hh2, row, f32));
            wxv[q][r] = isP ? ld(w_ih1, row, f32) : 0.0f;
        }
    // cell mapping: lane -> (batch cb, unit 16gw+uo)
    const int cb = lane >> 4;
    const int uo = lane & 15;
    const int cidx = srow(lane) * 4;
    const float wl_u = ld(w_lin, 16 * gw + uo, f32);
    const float blin = ld(b_lin, 0, f32);
    float cst = 0.0f;                 // c1 (P) or c2 (Q)
    __syncthreads();   // xs + zeroed h bufs visible

    for (int t = 0; t <= Tt; ++t) {
        if (isP) {
            if (t < Tt) {
                // ---- a1(t) = W1.h1(t-1) + x_t*wx + b1 ----
                f32x4 acc[4];
                const float xt = xs[(m & (NBat - 1)) * XSTR + t];
#pragma unroll
                for (int q = 0; q < 4; ++q)
#pragma unroll
                    for (int r = 0; r < 4; ++r)
                        acc[q][r] = fmaf(xt, wxv[q][r], bv[q][r]);
                if (t > 0) {
                    const _Float16* hp = h1buf[(t - 1) & 1] + m * HSTR;
                    const f16x8 ba = *(const f16x8*)(hp + quad * 8);
                    const f16x8 bb2 = *(const f16x8*)(hp + 32 + quad * 8);
#pragma unroll
                    for (int q = 0; q < 4; ++q) {
                        acc[q] = __builtin_amdgcn_mfma_f32_16x16x32_f16(wfA[q][0], ba, acc[q], 0, 0, 0);
                        acc[q] = __builtin_amdgcn_mfma_f32_16x16x32_f16(wfA[q][1], bb2, acc[q], 0, 0, 0);
                    }
                }
                if (m < NBat)
#pragma unroll
                    for (int q = 0; q < 4; ++q)
                        *(f32x4*)&scr1[gw][srow(m * 16 + q * 4 + quad) * 4] = acc[q];
                // ---- cell1(t): 1 eval/lane ----
                const f32x4 g = *(const f32x4*)&scr1[gw][cidx];   // i,f,g,o
                float ig = sigm(g[0]), fg = sigm(g[1]);
                float gg = tanh_f(g[2]), og = sigm(g[3]);
                cst = fmaf(fg, cst, ig * gg);
                h1buf[t & 1][cb * HSTR + 16 * gw + uo] = (_Float16)(og * tanh_f(cst));
            }
        } else {
            if (t > 0) {
                // ---- finalize out(t-2) in MFMA shadow ----
                if (t > 1 && w == 4 && lane < NBat) {
                    float s = blin;
#pragma unroll
                    for (int k = 0; k < 4; ++k) s += headl[t & 1][k * 4 + lane];
                    st(out, (bb + lane) * Tt + (t - 2), s, f32);
                }
                // ---- a2(t-1) = W2.h1(t-1) + W3.h2(t-2) + b2 ----
                const _Float16* h1p = h1buf[(t - 1) & 1] + m * HSTR;
                const _Float16* h2p = h2buf[t & 1] + m * HSTR;
                const f16x8 b1a = *(const f16x8*)(h1p + quad * 8);
                const f16x8 b1b = *(const f16x8*)(h1p + 32 + quad * 8);
                const f16x8 b2a = *(const f16x8*)(h2p + quad * 8);
                const f16x8 b2b = *(const f16x8*)(h2p + 32 + quad * 8);
                f32x4 acc[4];
#pragma unroll
                for (int q = 0; q < 4; ++q) {
                    f32x4 p = __builtin_amdgcn_mfma_f32_16x16x32_f16(wfA[q][0], b1a, bv[q], 0, 0, 0);
                    p = __builtin_amdgcn_mfma_f32_16x16x32_f16(wfA[q][1], b1b, p, 0, 0, 0);
                    p = __builtin_amdgcn_mfma_f32_16x16x32_f16(wfB[q][0], b2a, p, 0, 0, 0);
                    acc[q] = __builtin_amdgcn_mfma_f32_16x16x32_f16(wfB[q][1], b2b, p, 0, 0, 0);
                }
                if (m < NBat)
#pragma unroll
                    for (int q = 0; q < 4; ++q)
                        *(f32x4*)&scr2[gw][srow(m * 16 + q * 4 + quad) * 4] = acc[q];
                // ---- cell2(t-1): 1 eval/lane + head partial ----
                const f32x4 g = *(const f32x4*)&scr2[gw][cidx];
                float ig = sigm(g[0]), fg = sigm(g[1]);
                float gg = tanh_f(g[2]), og = sigm(g[3]);
                cst = fmaf(fg, cst, ig * gg);
                float h = og * tanh_f(cst);
                h2buf[(t - 1) & 1][cb * HSTR + 16 * gw + uo] = (_Float16)h;
                float p = h * wl_u;               // reduce over uo (same cb)
                p += __shfl_xor(p, 1); p += __shfl_xor(p, 2);
                p += __shfl_xor(p, 4); p += __shfl_xor(p, 8);
                if (uo == 0) headl[(t - 1) & 1][gw * 4 + cb] = p;
            }
        }
        __syncthreads();   // interval barrier: h1(t), h2(t-1), headl(t-1) visible
    }

    // ---- final: out(Tt-1) from headl[(Tt-1)&1] ----
    if (w == 4 && lane < NBat) {
        float s = blin;
#pragma unroll
        for (int k = 0; k < 4; ++k) s += headl[(Tt - 1) & 1][k * 4 + lane];
        st(out, (bb + lane) * Tt + (Tt - 1), s, f32);
    }
}

extern "C" void kernel_launch(void* const* d_in, const int* in_sizes, int n_in,
                              void* d_out, int out_size, void* d_ws, size_t ws_size,
                              hipStream_t stream)
{
    (void)in_sizes; (void)n_in; (void)out_size; (void)d_ws; (void)ws_size;
    lstm2_kernel<<<dim3(Bb / NBat), dim3(512), 0, stream>>>(
        d_in[0], d_in[1], d_in[2], d_in[3], d_in[4], d_in[5],
        d_in[6], d_in[7], d_in[8], d_in[9], d_in[10], d_out);
}